// Round 1
// baseline (218.258 us; speedup 1.0000x reference)
//
#include <hip/hip_runtime.h>
#include <hip/hip_bf16.h>

#define S_LEN 2048
#define BATCH 2
#define DMODEL 1024
#define NHEAD 16
#define HDIM 64
#define MTOT (S_LEN * BATCH)                 // 4096 rows in projection GEMMs
#define QKV_ELEMS ((size_t)MTOT * DMODEL)    // elements per projected tensor

typedef __bf16 bf16x8 __attribute__((ext_vector_type(8)));
typedef unsigned short u16x8 __attribute__((ext_vector_type(8)));
typedef float f32x4 __attribute__((ext_vector_type(4)));

__device__ __forceinline__ unsigned short f2bf(float f) {
    // round-to-nearest-even fp32 -> bf16
    unsigned int u = __float_as_uint(f);
    u += 0x7FFFu + ((u >> 16) & 1u);
    return (unsigned short)(u >> 16);
}

// ---------------------------------------------------------------------------
// Projection GEMM: C[m][n] = sum_k X[m][k] * W[n][k] + b[n]   (x @ W^T + b)
// m = s*B + b_idx (4096), n = h*64 + dd (1024), K = 1024.
// Output written as bf16 to ws in [b][h][s][d] layout; Q scaled by 1/8.
// 128x128 tile, BK=32, 4 waves (2x2), each wave 64x64 via 4x4 16x16x32 MFMA.
// ---------------------------------------------------------------------------
#define PBM 128
#define PBN 128
#define PBK 32
#define PLDS 48   // padded LDS row stride (bf16 elems): 96B, 16B-aligned b128

__global__ __launch_bounds__(256) void proj_kernel(
        const float* __restrict__ Xq, const float* __restrict__ Xk,
        const float* __restrict__ Xv, const float* __restrict__ Wq,
        const float* __restrict__ Wk, const float* __restrict__ Wv,
        const float* __restrict__ bq, const float* __restrict__ bk,
        const float* __restrict__ bv, unsigned short* __restrict__ ws)
{
    const int t = blockIdx.z;
    const float* X    = (t == 0) ? Xq : (t == 1) ? Xk : Xv;
    const float* W    = (t == 0) ? Wq : (t == 1) ? Wk : Wv;
    const float* bias = (t == 0) ? bq : (t == 1) ? bk : bv;
    unsigned short* out = ws + (size_t)t * QKV_ELEMS;
    const float scale = (t == 0) ? 0.125f : 1.0f;   // fold 1/sqrt(64) into Q

    __shared__ __align__(16) unsigned short lds[(PBM + PBN) * PLDS];
    unsigned short* Alds = lds;
    unsigned short* Blds = lds + PBM * PLDS;

    const int tid = threadIdx.x;
    const int m0 = blockIdx.y * PBM;
    const int n0 = blockIdx.x * PBN;

    const int wave = tid >> 6;
    const int lane = tid & 63;
    const int lrow = lane & 15;
    const int lg   = lane >> 4;
    const int wr = (wave >> 1) * 64;
    const int wc = (wave & 1) * 64;

    f32x4 acc[4][4];
#pragma unroll
    for (int i = 0; i < 4; ++i)
#pragma unroll
        for (int j = 0; j < 4; ++j)
            acc[i][j] = (f32x4){0.f, 0.f, 0.f, 0.f};

    const int sr = tid >> 3;   // staging row 0..31 (+32*it)
    const int sg = tid & 7;    // staging col group (4 floats each)

    for (int k0 = 0; k0 < DMODEL; k0 += PBK) {
        __syncthreads();
        // stage A (X tile) and B (W tile), fp32 -> bf16
#pragma unroll
        for (int it = 0; it < 4; ++it) {
            const int row = sr + it * 32;
            const float4 va = *(const float4*)(X + (size_t)(m0 + row) * DMODEL + k0 + sg * 4);
            const float4 vb = *(const float4*)(W + (size_t)(n0 + row) * DMODEL + k0 + sg * 4);
            ushort4 ha, hb;
            ha.x = f2bf(va.x); ha.y = f2bf(va.y); ha.z = f2bf(va.z); ha.w = f2bf(va.w);
            hb.x = f2bf(vb.x); hb.y = f2bf(vb.y); hb.z = f2bf(vb.z); hb.w = f2bf(vb.w);
            *(ushort4*)&Alds[row * PLDS + sg * 4] = ha;
            *(ushort4*)&Blds[row * PLDS + sg * 4] = hb;
        }
        __syncthreads();

        bf16x8 af[4], bw[4];
#pragma unroll
        for (int i = 0; i < 4; ++i) {
            af[i] = *(const bf16x8*)&Alds[(wr + i * 16 + lrow) * PLDS + lg * 8];
            bw[i] = *(const bf16x8*)&Blds[(wc + i * 16 + lrow) * PLDS + lg * 8];
        }
#pragma unroll
        for (int i = 0; i < 4; ++i)
#pragma unroll
            for (int j = 0; j < 4; ++j)
                acc[i][j] = __builtin_amdgcn_mfma_f32_16x16x32_bf16(af[i], bw[j], acc[i][j], 0, 0, 0);
    }

    // epilogue: +bias, *scale, bf16, write [b][h][s][d]
#pragma unroll
    for (int j = 0; j < 4; ++j) {
        const int n  = n0 + wc + j * 16 + lrow;
        const float bv_ = bias[n];
        const int h  = n >> 6;
        const int dd = n & 63;
#pragma unroll
        for (int i = 0; i < 4; ++i) {
#pragma unroll
            for (int r = 0; r < 4; ++r) {
                const int m = m0 + wr + i * 16 + lg * 4 + r;
                const int s = m >> 1;
                const int b = m & 1;
                const float v = (acc[i][j][r] + bv_) * scale;
                out[(size_t)((b * NHEAD + h) * S_LEN + s) * HDIM + dd] = f2bf(v);
            }
        }
    }
}

// ---------------------------------------------------------------------------
// Flash attention: per block one (b,h) and 128 q-rows (32 per wave).
// KV tiles of 64. K in LDS [key][d] stride 72; V in LDS transposed [d][key]
// stride 72 (pad => 2-way bank conflicts only, 16B-aligned b128).
// Scores: mfma(Q, K) -> frag row=q (lg*4+reg), col=key (lrow).
// Softmax reduced across the 16 lanes of each lg-group via shfl_xor.
// P -> bf16 -> per-wave LDS -> A-frags for PV mfma.
// ---------------------------------------------------------------------------
#define QT 128
#define KT 64
#define KSTR 72   // 144B row stride: 16B-aligned, 2-way conflicts

__device__ __forceinline__ f32x4 grp16_max(f32x4 v) {
#pragma unroll
    for (int m = 1; m <= 8; m <<= 1) {
        v[0] = fmaxf(v[0], __shfl_xor(v[0], m, 64));
        v[1] = fmaxf(v[1], __shfl_xor(v[1], m, 64));
        v[2] = fmaxf(v[2], __shfl_xor(v[2], m, 64));
        v[3] = fmaxf(v[3], __shfl_xor(v[3], m, 64));
    }
    return v;
}

__device__ __forceinline__ f32x4 grp16_sum(f32x4 v) {
#pragma unroll
    for (int m = 1; m <= 8; m <<= 1) {
        v[0] += __shfl_xor(v[0], m, 64);
        v[1] += __shfl_xor(v[1], m, 64);
        v[2] += __shfl_xor(v[2], m, 64);
        v[3] += __shfl_xor(v[3], m, 64);
    }
    return v;
}

__global__ __launch_bounds__(256) void attn_kernel(
        const unsigned short* __restrict__ ws, float* __restrict__ out)
{
    const unsigned short* Qw = ws;
    const unsigned short* Kw = ws + QKV_ELEMS;
    const unsigned short* Vw = ws + 2 * QKV_ELEMS;

    const int bh = blockIdx.y;              // b*16 + h
    const int q0 = blockIdx.x * QT;

    __shared__ __align__(16) unsigned short Klds[KT * KSTR];
    __shared__ __align__(16) unsigned short Vlds[HDIM * KSTR];   // [d][key]
    __shared__ __align__(16) unsigned short Plds[4][32 * KSTR];  // per wave

    const int tid  = threadIdx.x;
    const int wave = tid >> 6;
    const int lane = tid & 63;
    const int lrow = lane & 15;
    const int lg   = lane >> 4;

    const size_t base = (size_t)bh * S_LEN * HDIM;

    // Q fragments (rows q0+wave*32 .. +32), Q already scaled by 1/8
    bf16x8 qf[2][2];
#pragma unroll
    for (int rb = 0; rb < 2; ++rb)
#pragma unroll
        for (int kf = 0; kf < 2; ++kf)
            qf[rb][kf] = *(const bf16x8*)(Qw + base
                + (size_t)(q0 + wave * 32 + rb * 16 + lrow) * HDIM + kf * 32 + lg * 8);

    f32x4 O[2][4];
    f32x4 mvec[2], lvec[2];
#pragma unroll
    for (int rb = 0; rb < 2; ++rb) {
#pragma unroll
        for (int cb = 0; cb < 4; ++cb)
            O[rb][cb] = (f32x4){0.f, 0.f, 0.f, 0.f};
        mvec[rb] = (f32x4){-__builtin_inff(), -__builtin_inff(), -__builtin_inff(), -__builtin_inff()};
        lvec[rb] = (f32x4){0.f, 0.f, 0.f, 0.f};
    }

    const int skey = tid >> 2;   // 0..63
    const int sc   = tid & 3;    // 16-elem chunk of the 64-wide row

    for (int s0 = 0; s0 < S_LEN; s0 += KT) {
        __syncthreads();
        // stage K [key][d]
        {
            const unsigned short* ksrc = Kw + base + (size_t)(s0 + skey) * HDIM + sc * 16;
            *(u16x8*)&Klds[skey * KSTR + sc * 16]     = *(const u16x8*)(ksrc);
            *(u16x8*)&Klds[skey * KSTR + sc * 16 + 8] = *(const u16x8*)(ksrc + 8);
        }
        // stage V transposed [d][key]
        {
            const unsigned short* vsrc = Vw + base + (size_t)(s0 + skey) * HDIM + sc * 16;
            const u16x8 v0 = *(const u16x8*)(vsrc);
            const u16x8 v1 = *(const u16x8*)(vsrc + 8);
#pragma unroll
            for (int e = 0; e < 8; ++e) {
                Vlds[(sc * 16 + e) * KSTR + skey]     = v0[e];
                Vlds[(sc * 16 + 8 + e) * KSTR + skey] = v1[e];
            }
        }
        __syncthreads();

        // scores S[32][64] per wave
        f32x4 s_[2][4];
#pragma unroll
        for (int rb = 0; rb < 2; ++rb)
#pragma unroll
            for (int cf = 0; cf < 4; ++cf)
                s_[rb][cf] = (f32x4){0.f, 0.f, 0.f, 0.f};
#pragma unroll
        for (int cf = 0; cf < 4; ++cf) {
            const bf16x8 kb0 = *(const bf16x8*)&Klds[(cf * 16 + lrow) * KSTR + lg * 8];
            const bf16x8 kb1 = *(const bf16x8*)&Klds[(cf * 16 + lrow) * KSTR + 32 + lg * 8];
#pragma unroll
            for (int rb = 0; rb < 2; ++rb) {
                s_[rb][cf] = __builtin_amdgcn_mfma_f32_16x16x32_bf16(qf[rb][0], kb0, s_[rb][cf], 0, 0, 0);
                s_[rb][cf] = __builtin_amdgcn_mfma_f32_16x16x32_bf16(qf[rb][1], kb1, s_[rb][cf], 0, 0, 0);
            }
        }

        // online softmax (rows live in lg-group of 16 lanes; 4 rows per lane in regs)
#pragma unroll
        for (int rb = 0; rb < 2; ++rb) {
            f32x4 tmax = s_[rb][0];
#pragma unroll
            for (int cf = 1; cf < 4; ++cf) {
                tmax[0] = fmaxf(tmax[0], s_[rb][cf][0]);
                tmax[1] = fmaxf(tmax[1], s_[rb][cf][1]);
                tmax[2] = fmaxf(tmax[2], s_[rb][cf][2]);
                tmax[3] = fmaxf(tmax[3], s_[rb][cf][3]);
            }
            tmax = grp16_max(tmax);
            f32x4 mnew, ex;
#pragma unroll
            for (int r = 0; r < 4; ++r) {
                mnew[r] = fmaxf(mvec[rb][r], tmax[r]);
                ex[r]   = __expf(mvec[rb][r] - mnew[r]);
                mvec[rb][r] = mnew[r];
            }
            f32x4 psum = (f32x4){0.f, 0.f, 0.f, 0.f};
#pragma unroll
            for (int cf = 0; cf < 4; ++cf) {
#pragma unroll
                for (int r = 0; r < 4; ++r) {
                    const float p = __expf(s_[rb][cf][r] - mnew[r]);
                    psum[r] += p;
                    Plds[wave][(rb * 16 + lg * 4 + r) * KSTR + cf * 16 + lrow] = f2bf(p);
                }
            }
            psum = grp16_sum(psum);
#pragma unroll
            for (int r = 0; r < 4; ++r)
                lvec[rb][r] = lvec[rb][r] * ex[r] + psum[r];
#pragma unroll
            for (int cb = 0; cb < 4; ++cb)
#pragma unroll
                for (int r = 0; r < 4; ++r)
                    O[rb][cb][r] *= ex[r];
        }
        __asm__ volatile("" ::: "memory");   // order P writes before PV reads

        // PV: O += P(32xKT) * V(KTx64)
#pragma unroll
        for (int kf = 0; kf < 2; ++kf) {
            bf16x8 pa[2];
#pragma unroll
            for (int rb = 0; rb < 2; ++rb)
                pa[rb] = *(const bf16x8*)&Plds[wave][(rb * 16 + lrow) * KSTR + kf * 32 + lg * 8];
#pragma unroll
            for (int cb = 0; cb < 4; ++cb) {
                const bf16x8 vbf = *(const bf16x8*)&Vlds[(cb * 16 + lrow) * KSTR + kf * 32 + lg * 8];
#pragma unroll
                for (int rb = 0; rb < 2; ++rb)
                    O[rb][cb] = __builtin_amdgcn_mfma_f32_16x16x32_bf16(pa[rb], vbf, O[rb][cb], 0, 0, 0);
            }
        }
    }

    // normalize and write fp32 out[s][b][h*64+dd]
    const int bb = bh >> 4;
    const int hh = bh & 15;
#pragma unroll
    for (int rb = 0; rb < 2; ++rb) {
#pragma unroll
        for (int r = 0; r < 4; ++r) {
            const int qg = q0 + wave * 32 + rb * 16 + lg * 4 + r;
            const float inv = 1.0f / lvec[rb][r];
            float* op = out + (size_t)qg * (BATCH * DMODEL) + bb * DMODEL + hh * HDIM;
#pragma unroll
            for (int cb = 0; cb < 4; ++cb)
                op[cb * 16 + lrow] = O[rb][cb][r] * inv;
        }
    }
}

extern "C" void kernel_launch(void* const* d_in, const int* in_sizes, int n_in,
                              void* d_out, int out_size, void* d_ws, size_t ws_size,
                              hipStream_t stream) {
    const float* q  = (const float*)d_in[0];
    const float* k  = (const float*)d_in[1];
    const float* v  = (const float*)d_in[2];
    const float* Wq = (const float*)d_in[3];
    const float* bq = (const float*)d_in[4];
    const float* Wk = (const float*)d_in[5];
    const float* bk = (const float*)d_in[6];
    const float* Wv = (const float*)d_in[7];
    const float* bv = (const float*)d_in[8];
    unsigned short* ws = (unsigned short*)d_ws;  // 3 * 8 MB bf16 Q,K,V [b][h][s][d]
    float* out = (float*)d_out;

    dim3 pgrid(DMODEL / PBN, MTOT / PBM, 3);   // (8, 32, 3)
    proj_kernel<<<pgrid, dim3(256), 0, stream>>>(q, k, v, Wq, Wk, Wv, bq, bk, bv, ws);

    dim3 agrid(S_LEN / QT, BATCH * NHEAD);     // (16, 32)
    attn_kernel<<<agrid, dim3(256), 0, stream>>>(ws, out);
}

// Round 2
// 214.878 us; speedup vs baseline: 1.0157x; 1.0157x over previous
//
#include <hip/hip_runtime.h>
#include <hip/hip_bf16.h>

#define S_LEN 2048
#define BATCH 2
#define DMODEL 1024
#define NHEAD 16
#define HDIM 64
#define MTOT (S_LEN * BATCH)                 // 4096 rows in projection GEMMs
#define QKV_ELEMS ((size_t)MTOT * DMODEL)    // elements per projected tensor

typedef __bf16 bf16x8 __attribute__((ext_vector_type(8)));
typedef unsigned short u16x8 __attribute__((ext_vector_type(8)));
typedef float f32x4 __attribute__((ext_vector_type(4)));

__device__ __forceinline__ unsigned short f2bf(float f) {
    unsigned int u = __float_as_uint(f);
    u += 0x7FFFu + ((u >> 16) & 1u);
    return (unsigned short)(u >> 16);
}

// ---------------------------------------------------------------------------
// Projection GEMM: C[m][n] = X[m][:] . W[n][:] + b[n]   (x @ W^T + b)
// Q out: [b][h][s][d], scaled by 0.125*log2(e) (softmax done in base-2).
// K out: [b][h][s][d].  V out: [b][h][d][s]  (pre-transposed for attn PV).
// ---------------------------------------------------------------------------
#define PBM 128
#define PBN 128
#define PBK 32
#define PLDS 48

#define QSCALE 0.18033688011112042f   // 0.125 * log2(e)

__global__ __launch_bounds__(256) void proj_kernel(
        const float* __restrict__ Xq, const float* __restrict__ Xk,
        const float* __restrict__ Xv, const float* __restrict__ Wq,
        const float* __restrict__ Wk, const float* __restrict__ Wv,
        const float* __restrict__ bq, const float* __restrict__ bk,
        const float* __restrict__ bv, unsigned short* __restrict__ ws)
{
    const int t = blockIdx.z;
    const float* X    = (t == 0) ? Xq : (t == 1) ? Xk : Xv;
    const float* W    = (t == 0) ? Wq : (t == 1) ? Wk : Wv;
    const float* bias = (t == 0) ? bq : (t == 1) ? bk : bv;
    unsigned short* out = ws + (size_t)t * QKV_ELEMS;
    const float scale = (t == 0) ? QSCALE : 1.0f;

    __shared__ __align__(16) unsigned short lds[(PBM + PBN) * PLDS];
    unsigned short* Alds = lds;
    unsigned short* Blds = lds + PBM * PLDS;

    const int tid = threadIdx.x;
    const int m0 = blockIdx.y * PBM;
    const int n0 = blockIdx.x * PBN;

    const int wave = tid >> 6;
    const int lane = tid & 63;
    const int lrow = lane & 15;
    const int lg   = lane >> 4;
    const int wr = (wave >> 1) * 64;
    const int wc = (wave & 1) * 64;

    f32x4 acc[4][4];
#pragma unroll
    for (int i = 0; i < 4; ++i)
#pragma unroll
        for (int j = 0; j < 4; ++j)
            acc[i][j] = (f32x4){0.f, 0.f, 0.f, 0.f};

    const int sr = tid >> 3;
    const int sg = tid & 7;

    for (int k0 = 0; k0 < DMODEL; k0 += PBK) {
        __syncthreads();
#pragma unroll
        for (int it = 0; it < 4; ++it) {
            const int row = sr + it * 32;
            const float4 va = *(const float4*)(X + (size_t)(m0 + row) * DMODEL + k0 + sg * 4);
            const float4 vb = *(const float4*)(W + (size_t)(n0 + row) * DMODEL + k0 + sg * 4);
            ushort4 ha, hb;
            ha.x = f2bf(va.x); ha.y = f2bf(va.y); ha.z = f2bf(va.z); ha.w = f2bf(va.w);
            hb.x = f2bf(vb.x); hb.y = f2bf(vb.y); hb.z = f2bf(vb.z); hb.w = f2bf(vb.w);
            *(ushort4*)&Alds[row * PLDS + sg * 4] = ha;
            *(ushort4*)&Blds[row * PLDS + sg * 4] = hb;
        }
        __syncthreads();

        bf16x8 af[4], bw[4];
#pragma unroll
        for (int i = 0; i < 4; ++i) {
            af[i] = *(const bf16x8*)&Alds[(wr + i * 16 + lrow) * PLDS + lg * 8];
            bw[i] = *(const bf16x8*)&Blds[(wc + i * 16 + lrow) * PLDS + lg * 8];
        }
#pragma unroll
        for (int i = 0; i < 4; ++i)
#pragma unroll
            for (int j = 0; j < 4; ++j)
                acc[i][j] = __builtin_amdgcn_mfma_f32_16x16x32_bf16(af[i], bw[j], acc[i][j], 0, 0, 0);
    }

#pragma unroll
    for (int j = 0; j < 4; ++j) {
        const int n  = n0 + wc + j * 16 + lrow;
        const float bv_ = bias[n];
        const int h  = n >> 6;
        const int dd = n & 63;
#pragma unroll
        for (int i = 0; i < 4; ++i) {
#pragma unroll
            for (int r = 0; r < 4; ++r) {
                const int m = m0 + wr + i * 16 + lg * 4 + r;
                const int s = m >> 1;
                const int b = m & 1;
                const float v = (acc[i][j][r] + bv_) * scale;
                size_t idx;
                if (t == 2)  // V: [b][h][d][s] pre-transposed
                    idx = ((size_t)((b * NHEAD + h) * HDIM + dd)) * S_LEN + s;
                else         // Q,K: [b][h][s][d]
                    idx = ((size_t)((b * NHEAD + h) * S_LEN + s)) * HDIM + dd;
                out[idx] = f2bf(v);
            }
        }
    }
}

// ---------------------------------------------------------------------------
// Flash attention: 1024 blocks (XCD-swizzled), 4 waves x 16 q-rows = 64 q/block.
// K in LDS [key][d] stride 72 (2-way, free); V^T staged straight from the
// pre-transposed global layout into LDS [d][key] stride 72 (vector b128).
// Softmax base-2 (Q pre-scaled by log2e/8), reduced over 16-lane groups.
// ---------------------------------------------------------------------------
#define QT 64
#define KT 64
#define KSTR 72

__device__ __forceinline__ f32x4 grp16_max(f32x4 v) {
#pragma unroll
    for (int m = 1; m <= 8; m <<= 1) {
        v[0] = fmaxf(v[0], __shfl_xor(v[0], m, 64));
        v[1] = fmaxf(v[1], __shfl_xor(v[1], m, 64));
        v[2] = fmaxf(v[2], __shfl_xor(v[2], m, 64));
        v[3] = fmaxf(v[3], __shfl_xor(v[3], m, 64));
    }
    return v;
}

__device__ __forceinline__ f32x4 grp16_sum(f32x4 v) {
#pragma unroll
    for (int m = 1; m <= 8; m <<= 1) {
        v[0] += __shfl_xor(v[0], m, 64);
        v[1] += __shfl_xor(v[1], m, 64);
        v[2] += __shfl_xor(v[2], m, 64);
        v[3] += __shfl_xor(v[3], m, 64);
    }
    return v;
}

__global__ __launch_bounds__(256) void attn_kernel(
        const unsigned short* __restrict__ ws, float* __restrict__ out)
{
    const unsigned short* Qw = ws;
    const unsigned short* Kw = ws + QKV_ELEMS;
    const unsigned short* Vw = ws + 2 * QKV_ELEMS;   // [b][h][d][s]

    // XCD-aware swizzle: 4 bh per XCD (2 MB K/V fits 4 MB XCD L2)
    const int bid = blockIdx.x;
    const int xcd = bid & 7;
    const int idx = bid >> 3;              // 0..127
    const int bh  = xcd * 4 + (idx >> 5);  // 0..31
    const int q0  = (idx & 31) * QT;

    __shared__ __align__(16) unsigned short Klds[KT * KSTR];
    __shared__ __align__(16) unsigned short Vlds[HDIM * KSTR];   // [d][key]
    __shared__ __align__(16) unsigned short Plds[4][16 * KSTR];  // per wave

    const int tid  = threadIdx.x;
    const int wave = tid >> 6;
    const int lane = tid & 63;
    const int lrow = lane & 15;
    const int lg   = lane >> 4;

    const size_t base = (size_t)bh * S_LEN * HDIM;

    bf16x8 qf[2];
#pragma unroll
    for (int kf = 0; kf < 2; ++kf)
        qf[kf] = *(const bf16x8*)(Qw + base
            + (size_t)(q0 + wave * 16 + lrow) * HDIM + kf * 32 + lg * 8);

    f32x4 O[4];
#pragma unroll
    for (int cb = 0; cb < 4; ++cb)
        O[cb] = (f32x4){0.f, 0.f, 0.f, 0.f};
    f32x4 mvec = (f32x4){-__builtin_inff(), -__builtin_inff(), -__builtin_inff(), -__builtin_inff()};
    f32x4 lvec = (f32x4){0.f, 0.f, 0.f, 0.f};

    const int srow = tid >> 2;   // 0..63 (key for K, d for V)
    const int sc   = tid & 3;

    for (int s0 = 0; s0 < S_LEN; s0 += KT) {
        __syncthreads();
        {   // K tile [key][d]
            const unsigned short* ksrc = Kw + base + (size_t)(s0 + srow) * HDIM + sc * 16;
            *(u16x8*)&Klds[srow * KSTR + sc * 16]     = *(const u16x8*)(ksrc);
            *(u16x8*)&Klds[srow * KSTR + sc * 16 + 8] = *(const u16x8*)(ksrc + 8);
        }
        {   // V^T tile [d][key] — already transposed in global
            const unsigned short* vsrc = Vw + base + (size_t)srow * S_LEN + s0 + sc * 16;
            *(u16x8*)&Vlds[srow * KSTR + sc * 16]     = *(const u16x8*)(vsrc);
            *(u16x8*)&Vlds[srow * KSTR + sc * 16 + 8] = *(const u16x8*)(vsrc + 8);
        }
        __syncthreads();

        f32x4 s_[4];
#pragma unroll
        for (int cf = 0; cf < 4; ++cf)
            s_[cf] = (f32x4){0.f, 0.f, 0.f, 0.f};
#pragma unroll
        for (int cf = 0; cf < 4; ++cf) {
            const bf16x8 kb0 = *(const bf16x8*)&Klds[(cf * 16 + lrow) * KSTR + lg * 8];
            const bf16x8 kb1 = *(const bf16x8*)&Klds[(cf * 16 + lrow) * KSTR + 32 + lg * 8];
            s_[cf] = __builtin_amdgcn_mfma_f32_16x16x32_bf16(qf[0], kb0, s_[cf], 0, 0, 0);
            s_[cf] = __builtin_amdgcn_mfma_f32_16x16x32_bf16(qf[1], kb1, s_[cf], 0, 0, 0);
        }

        // online softmax, base-2 (scores already include log2e factor)
        {
            f32x4 tmax = s_[0];
#pragma unroll
            for (int cf = 1; cf < 4; ++cf) {
                tmax[0] = fmaxf(tmax[0], s_[cf][0]);
                tmax[1] = fmaxf(tmax[1], s_[cf][1]);
                tmax[2] = fmaxf(tmax[2], s_[cf][2]);
                tmax[3] = fmaxf(tmax[3], s_[cf][3]);
            }
            tmax = grp16_max(tmax);
            f32x4 mnew, ex;
#pragma unroll
            for (int r = 0; r < 4; ++r) {
                mnew[r] = fmaxf(mvec[r], tmax[r]);
                ex[r]   = exp2f(mvec[r] - mnew[r]);
                mvec[r] = mnew[r];
            }
            f32x4 psum = (f32x4){0.f, 0.f, 0.f, 0.f};
#pragma unroll
            for (int cf = 0; cf < 4; ++cf) {
#pragma unroll
                for (int r = 0; r < 4; ++r) {
                    const float p = exp2f(s_[cf][r] - mnew[r]);
                    psum[r] += p;
                    Plds[wave][(lg * 4 + r) * KSTR + cf * 16 + lrow] = f2bf(p);
                }
            }
            psum = grp16_sum(psum);
#pragma unroll
            for (int r = 0; r < 4; ++r)
                lvec[r] = lvec[r] * ex[r] + psum[r];
#pragma unroll
            for (int cb = 0; cb < 4; ++cb)
#pragma unroll
                for (int r = 0; r < 4; ++r)
                    O[cb][r] *= ex[r];
        }
        __asm__ volatile("" ::: "memory");

        // PV: O[16q x 64d] += P[16q x 64k] * V[64k x 64d]
#pragma unroll
        for (int kf = 0; kf < 2; ++kf) {
            const bf16x8 pa = *(const bf16x8*)&Plds[wave][lrow * KSTR + kf * 32 + lg * 8];
#pragma unroll
            for (int cb = 0; cb < 4; ++cb) {
                const bf16x8 vbf = *(const bf16x8*)&Vlds[(cb * 16 + lrow) * KSTR + kf * 32 + lg * 8];
                O[cb] = __builtin_amdgcn_mfma_f32_16x16x32_bf16(pa, vbf, O[cb], 0, 0, 0);
            }
        }
    }

    // normalize + write fp32 out[s][b][h*64+d]
    const int bb = bh >> 4;
    const int hh = bh & 15;
#pragma unroll
    for (int r = 0; r < 4; ++r) {
        const int qg = q0 + wave * 16 + lg * 4 + r;
        const float inv = 1.0f / lvec[r];
        float* op = out + (size_t)qg * (BATCH * DMODEL) + bb * DMODEL + hh * HDIM;
#pragma unroll
        for (int cb = 0; cb < 4; ++cb)
            op[cb * 16 + lrow] = O[cb][r] * inv;
    }
}

extern "C" void kernel_launch(void* const* d_in, const int* in_sizes, int n_in,
                              void* d_out, int out_size, void* d_ws, size_t ws_size,
                              hipStream_t stream) {
    const float* q  = (const float*)d_in[0];
    const float* k  = (const float*)d_in[1];
    const float* v  = (const float*)d_in[2];
    const float* Wq = (const float*)d_in[3];
    const float* bq = (const float*)d_in[4];
    const float* Wk = (const float*)d_in[5];
    const float* bk = (const float*)d_in[6];
    const float* Wv = (const float*)d_in[7];
    const float* bv = (const float*)d_in[8];
    unsigned short* ws = (unsigned short*)d_ws;
    float* out = (float*)d_out;

    dim3 pgrid(DMODEL / PBN, MTOT / PBM, 3);   // (8, 32, 3)
    proj_kernel<<<pgrid, dim3(256), 0, stream>>>(q, k, v, Wq, Wk, Wv, bq, bk, bv, ws);

    attn_kernel<<<dim3(1024), dim3(256), 0, stream>>>(ws, out);
}

// Round 4
// 157.705 us; speedup vs baseline: 1.3840x; 1.3625x over previous
//
#include <hip/hip_runtime.h>
#include <hip/hip_bf16.h>

#define S_LEN 2048
#define BATCH 2
#define DMODEL 1024
#define NHEAD 16
#define HDIM 64
#define MTOT (S_LEN * BATCH)
#define QKV_ELEMS ((size_t)MTOT * DMODEL)

typedef __bf16 bf16x8 __attribute__((ext_vector_type(8)));
typedef unsigned short u16x8 __attribute__((ext_vector_type(8)));
typedef float f32x4 __attribute__((ext_vector_type(4)));
typedef float f32x16 __attribute__((ext_vector_type(16)));
typedef unsigned int u32x4 __attribute__((ext_vector_type(4)));

__device__ __forceinline__ unsigned short f2bf(float f) {
    unsigned int u = __float_as_uint(f);
    u += 0x7FFFu + ((u >> 16) & 1u);
    return (unsigned short)(u >> 16);
}

// ---------------------------------------------------------------------------
// Projection GEMM (unchanged, verified in R1/R2): x @ W^T + b, bf16 out.
// Q: [b][h][s][d] scaled by 0.125*log2(e).  K: [b][h][s][d].  V: [b][h][d][s].
// ---------------------------------------------------------------------------
#define PBM 128
#define PBN 128
#define PBK 32
#define PLDS 48
#define QSCALE 0.18033688011112042f   // 0.125 * log2(e)

__global__ __launch_bounds__(256) void proj_kernel(
        const float* __restrict__ Xq, const float* __restrict__ Xk,
        const float* __restrict__ Xv, const float* __restrict__ Wq,
        const float* __restrict__ Wk, const float* __restrict__ Wv,
        const float* __restrict__ bq, const float* __restrict__ bk,
        const float* __restrict__ bv, unsigned short* __restrict__ ws)
{
    const int t = blockIdx.z;
    const float* X    = (t == 0) ? Xq : (t == 1) ? Xk : Xv;
    const float* W    = (t == 0) ? Wq : (t == 1) ? Wk : Wv;
    const float* bias = (t == 0) ? bq : (t == 1) ? bk : bv;
    unsigned short* out = ws + (size_t)t * QKV_ELEMS;
    const float scale = (t == 0) ? QSCALE : 1.0f;

    __shared__ __align__(16) unsigned short lds[(PBM + PBN) * PLDS];
    unsigned short* Alds = lds;
    unsigned short* Blds = lds + PBM * PLDS;

    const int tid = threadIdx.x;
    const int m0 = blockIdx.y * PBM;
    const int n0 = blockIdx.x * PBN;

    const int wave = tid >> 6;
    const int lane = tid & 63;
    const int lrow = lane & 15;
    const int lg   = lane >> 4;
    const int wr = (wave >> 1) * 64;
    const int wc = (wave & 1) * 64;

    f32x4 acc[4][4];
#pragma unroll
    for (int i = 0; i < 4; ++i)
#pragma unroll
        for (int j = 0; j < 4; ++j)
            acc[i][j] = (f32x4){0.f, 0.f, 0.f, 0.f};

    const int sr = tid >> 3;
    const int sg = tid & 7;

    for (int k0 = 0; k0 < DMODEL; k0 += PBK) {
        __syncthreads();
#pragma unroll
        for (int it = 0; it < 4; ++it) {
            const int row = sr + it * 32;
            const float4 va = *(const float4*)(X + (size_t)(m0 + row) * DMODEL + k0 + sg * 4);
            const float4 vb = *(const float4*)(W + (size_t)(n0 + row) * DMODEL + k0 + sg * 4);
            ushort4 ha, hb;
            ha.x = f2bf(va.x); ha.y = f2bf(va.y); ha.z = f2bf(va.z); ha.w = f2bf(va.w);
            hb.x = f2bf(vb.x); hb.y = f2bf(vb.y); hb.z = f2bf(vb.z); hb.w = f2bf(vb.w);
            *(ushort4*)&Alds[row * PLDS + sg * 4] = ha;
            *(ushort4*)&Blds[row * PLDS + sg * 4] = hb;
        }
        __syncthreads();

        bf16x8 af[4], bw[4];
#pragma unroll
        for (int i = 0; i < 4; ++i) {
            af[i] = *(const bf16x8*)&Alds[(wr + i * 16 + lrow) * PLDS + lg * 8];
            bw[i] = *(const bf16x8*)&Blds[(wc + i * 16 + lrow) * PLDS + lg * 8];
        }
#pragma unroll
        for (int i = 0; i < 4; ++i)
#pragma unroll
            for (int j = 0; j < 4; ++j)
                acc[i][j] = __builtin_amdgcn_mfma_f32_16x16x32_bf16(af[i], bw[j], acc[i][j], 0, 0, 0);
    }

#pragma unroll
    for (int j = 0; j < 4; ++j) {
        const int n  = n0 + wc + j * 16 + lrow;
        const float bv_ = bias[n];
        const int h  = n >> 6;
        const int dd = n & 63;
#pragma unroll
        for (int i = 0; i < 4; ++i) {
#pragma unroll
            for (int r = 0; r < 4; ++r) {
                const int m = m0 + wr + i * 16 + lg * 4 + r;
                const int s = m >> 1;
                const int b = m & 1;
                const float v = (acc[i][j][r] + bv_) * scale;
                size_t idx;
                if (t == 2)
                    idx = ((size_t)((b * NHEAD + h) * HDIM + dd)) * S_LEN + s;
                else
                    idx = ((size_t)((b * NHEAD + h) * S_LEN + s)) * HDIM + dd;
                out[idx] = f2bf(v);
            }
        }
    }
}

// ---------------------------------------------------------------------------
// Flash attention, swapped-QK^T 32x32 structure:
//   S^T = mfma32x32x16(K, Q^T): lane holds one q-column -> softmax in-register
//   (per-lane fmax/add over 32 regs + one shfl_xor(32) cross-half combine).
//   P^T -> bf16 via bit-ops, packed u32 pairs through per-wave LDS; read back
//   with the SAME slot->key map as the V fragments, so PV is invariant to the
//   (unverified) A/B k-layout, exactly like QK^T.  C/D layout per m74/m101.
//   K [key][d], V^T [d][key] in XOR-swizzled LDS (conflict-free b128 reads).
// ---------------------------------------------------------------------------
__global__ __launch_bounds__(512) void attn_kernel(
        const unsigned short* __restrict__ ws, float* __restrict__ out)
{
    const unsigned short* Qw = ws;
    const unsigned short* Kw = ws + QKV_ELEMS;
    const unsigned short* Vw = ws + 2 * QKV_ELEMS;   // [b][h][d][s]

    const int bid = blockIdx.x;
    const int idx = bid >> 3;
    const int bh  = (bid & 7) * 4 + (idx >> 3);      // 4 bh per XCD
    const int q0  = (idx & 7) * 256;

    __shared__ __align__(16) unsigned short Klds[64 * 64];
    __shared__ __align__(16) unsigned short Vlds[64 * 64];
    __shared__ unsigned int Pu[8][32 * 32];          // per-wave [keypair][q]

    const int tid  = threadIdx.x;
    const int wave = tid >> 6;
    const int lane = tid & 63;
    const int l31  = lane & 31;
    const int half = lane >> 5;

    const size_t base = (size_t)bh * S_LEN * HDIM;
    const int qrow = q0 + wave * 32 + l31;

    // Q^T B-fragments: lane covers q = l31, d = c*16 + half*8 + j
    bf16x8 qf[4];
#pragma unroll
    for (int c = 0; c < 4; ++c)
        qf[c] = *(const bf16x8*)(Qw + base + (size_t)qrow * HDIM + c * 16 + half * 8);

    f32x16 Od0, Od1;
#pragma unroll
    for (int i = 0; i < 16; ++i) { Od0[i] = 0.f; Od1[i] = 0.f; }
    float mrun = -__builtin_inff();
    float lrun = 0.f;

    const int srow = tid >> 3;   // 0..63 staging row
    const int sg   = tid & 7;    // 8-elem group within 64-elem row

    for (int s0 = 0; s0 < S_LEN; s0 += 64) {
        __syncthreads();
        {
            const int gsw = (sg ^ (srow & 7)) * 8;
            *(u16x8*)&Klds[srow * 64 + gsw] =
                *(const u16x8*)(Kw + base + (size_t)(s0 + srow) * HDIM + sg * 8);
            *(u16x8*)&Vlds[srow * 64 + gsw] =
                *(const u16x8*)(Vw + base + (size_t)srow * S_LEN + s0 + sg * 8);
        }
        __syncthreads();

        // S^T = K . Q^T (two 32-key tiles); A and B share the slot->k map.
        f32x16 S0, S1;
#pragma unroll
        for (int i = 0; i < 16; ++i) { S0[i] = 0.f; S1[i] = 0.f; }
#pragma unroll
        for (int c = 0; c < 4; ++c) {
            const int g = ((c * 2 + half) ^ (l31 & 7)) * 8;
            const bf16x8 ka0 = *(const bf16x8*)&Klds[l31 * 64 + g];
            const bf16x8 ka1 = *(const bf16x8*)&Klds[(32 + l31) * 64 + g];
            S0 = __builtin_amdgcn_mfma_f32_32x32x16_bf16(ka0, qf[c], S0, 0, 0, 0);
            S1 = __builtin_amdgcn_mfma_f32_32x32x16_bf16(ka1, qf[c], S1, 0, 0, 0);
        }

        // ---- in-register online softmax (base 2) ----
        float mx = S0[0];
#pragma unroll
        for (int i = 1; i < 16; ++i) mx = fmaxf(mx, S0[i]);
#pragma unroll
        for (int i = 0; i < 16; ++i) mx = fmaxf(mx, S1[i]);
        mx = fmaxf(mx, __shfl_xor(mx, 32, 64));      // combine lane halves

        const float mnew = fmaxf(mrun, mx);
        const float ex   = exp2f(mrun - mnew);
        mrun = mnew;

        float psum = 0.f;
#pragma unroll
        for (int i = 0; i < 16; ++i) { S0[i] = exp2f(S0[i] - mnew); psum += S0[i]; }
#pragma unroll
        for (int i = 0; i < 16; ++i) { S1[i] = exp2f(S1[i] - mnew); psum += S1[i]; }
        psum += __shfl_xor(psum, 32, 64);
        lrun = lrun * ex + psum;
        Od0 *= ex;
        Od1 *= ex;

        // ---- P^T -> per-wave LDS as packed key-pairs (C/D layout, m74/m101):
        // reg r holds key (r&3) + 8*(r>>2) + 4*half; regs (2w,2w+1) are the
        // adjacent-key pair kp = (w&1) + 4*(w>>1) + 2*half (lo = even key).
#pragma unroll
        for (int w = 0; w < 8; ++w) {
            const unsigned int pk0 = (unsigned int)f2bf(S0[2 * w])
                                   | ((unsigned int)f2bf(S0[2 * w + 1]) << 16);
            const unsigned int pk1 = (unsigned int)f2bf(S1[2 * w])
                                   | ((unsigned int)f2bf(S1[2 * w + 1]) << 16);
            const int kp = (w & 1) + 4 * (w >> 1) + 2 * half;
            Pu[wave][kp * 32 + l31]        = pk0;
            Pu[wave][(16 + kp) * 32 + l31] = pk1;
        }
        __asm__ volatile("" ::: "memory");

        // ---- PV: O^T[d][q] += V^T . P^T ----
        // P read uses slot(h,j) -> key = c*16 + 8h + j: identical map to V.
#pragma unroll
        for (int c = 0; c < 4; ++c) {
            const int g = ((c * 2 + half) ^ (l31 & 7)) * 8;
            const bf16x8 va0 = *(const bf16x8*)&Vlds[l31 * 64 + g];
            const bf16x8 va1 = *(const bf16x8*)&Vlds[(32 + l31) * 64 + g];
            u32x4 pu;
#pragma unroll
            for (int e = 0; e < 4; ++e)
                pu[e] = Pu[wave][(c * 8 + half * 4 + e) * 32 + l31];
            const bf16x8 pb = __builtin_bit_cast(bf16x8, pu);
            Od0 = __builtin_amdgcn_mfma_f32_32x32x16_bf16(va0, pb, Od0, 0, 0, 0);
            Od1 = __builtin_amdgcn_mfma_f32_32x32x16_bf16(va1, pb, Od1, 0, 0, 0);
        }
    }

    // epilogue: normalize, write fp32 out[s][b][h*64+d]
    const int bb = bh >> 4;
    const int hh = bh & 15;
    const float inv = 1.0f / lrun;
    float* op = out + (size_t)qrow * (BATCH * DMODEL) + bb * DMODEL + hh * HDIM;
#pragma unroll
    for (int gg = 0; gg < 4; ++gg) {
        const int d0 = gg * 8 + half * 4;
        float4 v0, v1;
        v0.x = Od0[gg * 4 + 0] * inv; v0.y = Od0[gg * 4 + 1] * inv;
        v0.z = Od0[gg * 4 + 2] * inv; v0.w = Od0[gg * 4 + 3] * inv;
        v1.x = Od1[gg * 4 + 0] * inv; v1.y = Od1[gg * 4 + 1] * inv;
        v1.z = Od1[gg * 4 + 2] * inv; v1.w = Od1[gg * 4 + 3] * inv;
        *(float4*)(op + d0)      = v0;
        *(float4*)(op + 32 + d0) = v1;
    }
}

extern "C" void kernel_launch(void* const* d_in, const int* in_sizes, int n_in,
                              void* d_out, int out_size, void* d_ws, size_t ws_size,
                              hipStream_t stream) {
    const float* q  = (const float*)d_in[0];
    const float* k  = (const float*)d_in[1];
    const float* v  = (const float*)d_in[2];
    const float* Wq = (const float*)d_in[3];
    const float* bq = (const float*)d_in[4];
    const float* Wk = (const float*)d_in[5];
    const float* bk = (const float*)d_in[6];
    const float* Wv = (const float*)d_in[7];
    const float* bv = (const float*)d_in[8];
    unsigned short* ws = (unsigned short*)d_ws;
    float* out = (float*)d_out;

    dim3 pgrid(DMODEL / PBN, MTOT / PBM, 3);
    proj_kernel<<<pgrid, dim3(256), 0, stream>>>(q, k, v, Wq, Wk, Wv, bq, bk, bv, ws);

    attn_kernel<<<dim3(256), dim3(512), 0, stream>>>(ws, out);
}